// Round 5
// baseline (1162.159 us; speedup 1.0000x reference)
//
#include <hip/hip_runtime.h>
#include <stdint.h>

#define NN 8192
#define MM 16
#define FN 128
#define HH 512

typedef unsigned short u16;
typedef unsigned int u32;
typedef __bf16 bf16;
typedef __bf16 bf16x8 __attribute__((ext_vector_type(8)));
typedef float f32x4 __attribute__((ext_vector_type(4)));

// async global->LDS, 16B/lane; LDS dest = wave-uniform base + lane*16
__device__ __forceinline__ void gld_lds16(const u16* g, u16* l) {
  __builtin_amdgcn_global_load_lds(
      (const __attribute__((address_space(1))) void*)g,
      (__attribute__((address_space(3))) void*)l, 16, 0, 0);
}

// ---- dtype probes (per-wave; ~2 cached loads + ballot) ----
__device__ __forceinline__ int probe_f32(const u16* w) {
  int lane = threadIdx.x & 63;
  int e = (w[2 * lane] >> 7) & 0xFF;
  unsigned long long m = __ballot(!(e == 0 || (e >= 90 && e <= 140)));
  return __popcll(m) >= 8;
}
__device__ __forceinline__ int probe_i64(const u32* w) {
  int lane = threadIdx.x & 63;
  unsigned long long m = __ballot(lane < 32 && w[2 * lane + 1] != 0);
  return m == 0;
}

// ---- device-scope producer/consumer sync (G16: agent-scope acq/rel) ----
__device__ __forceinline__ void bump(int* ctr) {
  __syncthreads();
  __threadfence();  // belt & suspenders: agent fence before release-add
  if (threadIdx.x == 0)
    __hip_atomic_fetch_add(ctr, 1, __ATOMIC_RELEASE, __HIP_MEMORY_SCOPE_AGENT);
}
__device__ __forceinline__ void wait_for(int* ctr, int target) {
  if (threadIdx.x == 0) {
    while (__hip_atomic_load(ctr, __ATOMIC_ACQUIRE, __HIP_MEMORY_SCOPE_AGENT) <
           target)
      __builtin_amdgcn_s_sleep(32);
  }
  __syncthreads();  // all waves held until data visible
}

// ---- GEMM tile body: C[rtile*64..+64][ctile*128..+128] = A @ Bt^T + bias
// 4 waves (2x2), wave 32x64 (2x4 accs of 16x16x32), BK=64, gld_lds + XOR
// swizzle: LDS chunk (row, cc) holds global k-chunk gc = cc ^ (row&7).
template <bool RELU>
__device__ __forceinline__ void gemm_tile(const void* __restrict__ A, int K,
                                          int af32, const u16* __restrict__ Bt,
                                          const u16* __restrict__ bias,
                                          int rtile, int ctile, int outf32,
                                          void* __restrict__ C, u16* As,
                                          u16* Bs) {
  const int tid = threadIdx.x;
  const int wave = tid >> 6, lane = tid & 63;
  const int wr = wave >> 1, wc = wave & 1;
  const int quad = lane >> 4, l16 = lane & 15;
  f32x4 acc[2][4] = {};

  int arow[2], agc[2], brow[4], bgc[4];
#pragma unroll
  for (int i = 0; i < 2; ++i) {
    int c = i * 256 + tid;
    arow[i] = c >> 3;
    agc[i] = (c & 7) ^ (arow[i] & 7);
  }
#pragma unroll
  for (int i = 0; i < 4; ++i) {
    int c = i * 256 + tid;
    brow[i] = c >> 3;
    bgc[i] = (c & 7) ^ (brow[i] & 7);
  }
  u16* AsW = As + wave * 512;  // wave-uniform LDS bases (chunk c -> c*16 B)
  u16* BsW = Bs + wave * 512;

  for (int k0 = 0; k0 < K; k0 += 64) {
    __syncthreads();  // prev iter's ds_reads done
    if (af32) {
      const float* Af = (const float*)A;
      bf16x8 v[2];
#pragma unroll
      for (int i = 0; i < 2; ++i) {
        const float* p = &Af[(size_t)(rtile * 64 + arow[i]) * K + k0 + agc[i] * 8];
        f32x4 x0 = *(const f32x4*)p, x1 = *(const f32x4*)(p + 4);
#pragma unroll
        for (int t = 0; t < 4; ++t) {
          v[i][t] = (bf16)x0[t];
          v[i][4 + t] = (bf16)x1[t];
        }
      }
#pragma unroll
      for (int i = 0; i < 2; ++i) *(bf16x8*)&As[(i * 256 + tid) * 8] = v[i];
    } else {
      const u16* Ab = (const u16*)A;
#pragma unroll
      for (int i = 0; i < 2; ++i)
        gld_lds16(&Ab[(size_t)(rtile * 64 + arow[i]) * K + k0 + agc[i] * 8],
                  AsW + i * 2048);
    }
#pragma unroll
    for (int i = 0; i < 4; ++i)
      gld_lds16(&Bt[(size_t)(ctile * 128 + brow[i]) * K + k0 + bgc[i] * 8],
                BsW + i * 2048);
    __syncthreads();  // drains vmcnt (DMA complete)
#pragma unroll
    for (int h = 0; h < 2; ++h) {
      bf16x8 af[2], bfr[4];
#pragma unroll
      for (int i = 0; i < 2; ++i) {
        int r = wr * 32 + i * 16 + l16;
        int cc = (h * 4 + quad) ^ (r & 7);
        af[i] = *(const bf16x8*)&As[r * 64 + cc * 8];
      }
#pragma unroll
      for (int j = 0; j < 4; ++j) {
        int n = wc * 64 + j * 16 + l16;
        int cc = (h * 4 + quad) ^ (n & 7);
        bfr[j] = *(const bf16x8*)&Bs[n * 64 + cc * 8];
      }
#pragma unroll
      for (int i = 0; i < 2; ++i)
#pragma unroll
        for (int j = 0; j < 4; ++j)
          acc[i][j] = __builtin_amdgcn_mfma_f32_16x16x32_bf16(af[i], bfr[j],
                                                              acc[i][j], 0, 0, 0);
    }
  }

  // C/D layout: col = lane&15, row = quad*4 + reg (m89/m91)
  const int crow0 = rtile * 64 + wr * 32 + quad * 4;
  const int ccol0 = ctile * 128 + wc * 64 + l16;
#pragma unroll
  for (int j = 0; j < 4; ++j) {
    const int col = ccol0 + j * 16;
    const float bv = (float)(*(const bf16*)&bias[col]);
#pragma unroll
    for (int i = 0; i < 2; ++i)
#pragma unroll
      for (int r = 0; r < 4; ++r) {
        float v = acc[i][j][r] + bv;
        if (RELU) v = fmaxf(v, 0.0f);
        size_t off = (size_t)(crow0 + i * 16 + r) * HH + col;
        if (outf32) {
          ((float*)C)[off] = v;
        } else {
          bf16 o = (bf16)v;
          ((u16*)C)[off] = *(u16*)&o;
        }
      }
  }
}

// ---- L1: prep (blocks 0..871) + emb GEMM (blocks 872..1383, spin on prep)
__global__ __launch_bounds__(256) void prep_emb_kernel(
    const u16* __restrict__ node, const u32* __restrict__ idxw,
    const void* __restrict__ Wemb, const void* __restrict__ b0,
    const void* __restrict__ W1, const void* __restrict__ b1,
    const void* __restrict__ W2, const void* __restrict__ b2,
    const void* __restrict__ W3, const void* __restrict__ b3,
    float* __restrict__ dis, u16* __restrict__ biasBF, u16* __restrict__ TWemb,
    u16* __restrict__ TW1, u16* __restrict__ TW2, u16* __restrict__ TW3,
    u16* __restrict__ xout, int* ctr) {
  __shared__ __align__(16) u16 As[64 * 64];
  __shared__ __align__(16) u16 Bs[128 * 64];
  const int bid = blockIdx.x, tid = threadIdx.x;
  if (bid < 872) {
    const int f32in = probe_f32(node);
    const int i64 = probe_i64(idxw);
    if (bid < 32) {
      const int i = bid * 256 + tid;
      const int* idx = (const int*)idxw;
      int c = 1;
#pragma unroll
      for (int e = 0; e < MM; ++e) c += (idx[(i * MM + e) << i64] >= 0) ? 1 : 0;
      dis[i] = rsqrtf((float)c);
    } else if (bid < 40) {
      const int id = (bid - 32) * 256 + tid;  // 0..2047
      const int q = id >> 9;
      const void* src = q == 0 ? b0 : q == 1 ? b1 : q == 2 ? b2 : b3;
      const int off = id & (HH - 1);
      bf16 v = f32in ? (bf16)((const float*)src)[off] : ((const bf16*)src)[off];
      biasBF[id] = *(u16*)&v;
    } else {
      int t = bid - 40;  // 0..831 transpose tiles (32x32)
      const void* W;
      u16* T;
      int K, tt;
      if (t < 64) {
        W = Wemb; T = TWemb; K = FN; tt = t;
      } else {
        int q = (t - 64) >> 8;
        tt = (t - 64) & 255;
        K = HH;
        W = q == 0 ? W1 : q == 1 ? W2 : W3;
        T = q == 0 ? TW1 : q == 1 ? TW2 : TW3;
      }
      const int k0 = (tt >> 4) * 32, n0 = (tt & 15) * 32;
      u16* sm = As;  // reuse (needs 32*33 u16)
      const int tx = tid & 31, ty = tid >> 5;
#pragma unroll
      for (int r = ty; r < 32; r += 8) {
        size_t src = (size_t)(k0 + r) * HH + n0 + tx;
        bf16 v = f32in ? (bf16)((const float*)W)[src] : ((const bf16*)W)[src];
        sm[r * 33 + tx] = *(u16*)&v;
      }
      __syncthreads();
#pragma unroll
      for (int r = ty; r < 32; r += 8)
        T[(size_t)(n0 + r) * K + k0 + tx] = sm[tx * 33 + r];
    }
    bump(ctr);
  } else {
    const int gb = bid - 872;  // 0..511
    const int af32 = probe_f32(node);
    wait_for(ctr, 872);
    gemm_tile<false>(node, FN, af32, TWemb, biasBF, gb >> 2, gb & 3, 0, xout,
                     As, Bs);
  }
}

// ---- layer: agg (blocks 0..2047) + GEMM (blocks 2048..2559, spin on agg)
template <bool RELU, bool FINAL>
__global__ __launch_bounds__(256) void layer_kernel(
    const u16* __restrict__ xin, const u32* __restrict__ idxw,
    const float* __restrict__ dis, const u16* __restrict__ Bt,
    const u16* __restrict__ bias, const u16* __restrict__ nodeprobe,
    u16* __restrict__ xmid, void* __restrict__ xout, int* ctr) {
  __shared__ __align__(16) u16 As[64 * 64];
  __shared__ __align__(16) u16 Bs[128 * 64];
  const int bid = blockIdx.x;
  if (bid < 2048) {
    // agg: y[i,:] = d[i]*( d[i]*x[i,:] + sum_e d[j]*x[j,:] ), wave/node
    const int i64 = probe_i64(idxw);
    const int* idx = (const int*)idxw;
    const int node = bid * 4 + (threadIdx.x >> 6);
    const int lane = threadIdx.x & 63;
    const int c0 = lane * 8;
    const float wi = dis[node];
    float acc[8];
    bf16x8 xs = *(const bf16x8*)&xin[(size_t)node * HH + c0];
#pragma unroll
    for (int t = 0; t < 8; ++t) acc[t] = wi * wi * (float)xs[t];
#pragma unroll
    for (int e = 0; e < MM; ++e) {
      const int j = idx[(node * MM + e) << i64];
      if (j >= 0) {
        const float w = wi * dis[j];
        bf16x8 v = *(const bf16x8*)&xin[(size_t)j * HH + c0];
#pragma unroll
        for (int t = 0; t < 8; ++t) acc[t] += w * (float)v[t];
      }
    }
    bf16x8 o;
#pragma unroll
    for (int t = 0; t < 8; ++t) o[t] = (bf16)acc[t];
    *(bf16x8*)&xmid[(size_t)node * HH + c0] = o;
    bump(ctr);
  } else {
    const int gb = bid - 2048;  // 0..511
    int outf32 = 0;
    if (FINAL) outf32 = probe_f32(nodeprobe);
    wait_for(ctr, 2048);
    gemm_tile<RELU>(xmid, HH, 0, Bt, bias, gb >> 2, gb & 3, outf32, xout, As,
                    Bs);
  }
}

extern "C" void kernel_launch(void* const* d_in, const int* in_sizes, int n_in,
                              void* d_out, int out_size, void* d_ws, size_t ws_size,
                              hipStream_t stream) {
  const u16* node = (const u16*)d_in[0];
  const u32* idxw = (const u32*)d_in[1];
  const void* Wemb = d_in[2];
  const void* bemb = d_in[3];
  const void* W1 = d_in[4];
  const void* b1 = d_in[5];
  const void* W2 = d_in[6];
  const void* b2 = d_in[7];
  const void* W3 = d_in[8];
  const void* b3 = d_in[9];

  char* p = (char*)d_ws;
  int* ctrs = (int*)p;     p += 256;
  float* dis = (float*)p;  p += NN * sizeof(float);
  u16* biasBF = (u16*)p;   p += 4 * HH * sizeof(u16);
  u16* TWemb = (u16*)p;    p += (size_t)HH * FN * 2;
  u16* TW1 = (u16*)p;      p += (size_t)HH * HH * 2;
  u16* TW2 = (u16*)p;      p += (size_t)HH * HH * 2;
  u16* TW3 = (u16*)p;      p += (size_t)HH * HH * 2;
  u16* xA = (u16*)p;       // 8 MB agg buffer
  u16* xO = (u16*)d_out;   // d_out doubles as bf16 ping buffer

  hipMemsetAsync(ctrs, 0, 4 * sizeof(int), stream);
  prep_emb_kernel<<<1384, 256, 0, stream>>>(node, idxw, Wemb, bemb, W1, b1, W2,
                                            b2, W3, b3, dis, biasBF, TWemb, TW1,
                                            TW2, TW3, xO, ctrs + 0);
  layer_kernel<true, false><<<2560, 256, 0, stream>>>(
      xO, idxw, dis, TW1, biasBF + HH, node, xA, xO, ctrs + 1);
  layer_kernel<true, false><<<2560, 256, 0, stream>>>(
      xO, idxw, dis, TW2, biasBF + 2 * HH, node, xA, xO, ctrs + 2);
  layer_kernel<false, true><<<2560, 256, 0, stream>>>(
      xO, idxw, dis, TW3, biasBF + 3 * HH, node, xA, d_out, ctrs + 3);
}

// Round 6
// 179.971 us; speedup vs baseline: 6.4575x; 6.4575x over previous
//
#include <hip/hip_runtime.h>
#include <stdint.h>

#define NN 8192
#define MM 16
#define FN 128
#define HH 512

typedef unsigned short u16;
typedef unsigned int u32;
typedef __bf16 bf16;
typedef __bf16 bf16x8 __attribute__((ext_vector_type(8)));
typedef float f32x4 __attribute__((ext_vector_type(4)));

// async global->LDS, 16B/lane; LDS dest = wave-uniform base + lane*16
__device__ __forceinline__ void gld_lds16(const u16* g, u16* l) {
  __builtin_amdgcn_global_load_lds(
      (const __attribute__((address_space(1))) void*)g,
      (__attribute__((address_space(3))) void*)l, 16, 0, 0);
}

// ---- dtype probes (per-wave; ~2 cached loads + ballot) ----
__device__ __forceinline__ int probe_f32(const u16* w) {
  int lane = threadIdx.x & 63;
  int e = (w[2 * lane] >> 7) & 0xFF;
  unsigned long long m = __ballot(!(e == 0 || (e >= 90 && e <= 140)));
  return __popcll(m) >= 8;
}
__device__ __forceinline__ int probe_i64(const u32* w) {
  int lane = threadIdx.x & 63;
  unsigned long long m = __ballot(lane < 32 && w[2 * lane + 1] != 0);
  return m == 0;
}

// ---- prep: deg (blocks 0..31) + bias cvt (32..39) + weight transpose (40..871)
__global__ __launch_bounds__(256) void prep_kernel(
    const u16* __restrict__ node, const u32* __restrict__ idxw,
    const void* __restrict__ Wemb, const void* __restrict__ b0,
    const void* __restrict__ W1, const void* __restrict__ b1,
    const void* __restrict__ W2, const void* __restrict__ b2,
    const void* __restrict__ W3, const void* __restrict__ b3,
    float* __restrict__ dis, u16* __restrict__ biasBF, u16* __restrict__ TWemb,
    u16* __restrict__ TW1, u16* __restrict__ TW2, u16* __restrict__ TW3) {
  const int f32in = probe_f32(node);
  const int i64 = probe_i64(idxw);
  const int bid = blockIdx.x, tid = threadIdx.x;
  if (bid < 32) {
    const int i = bid * 256 + tid;
    const int* idx = (const int*)idxw;
    int c = 1;
#pragma unroll
    for (int e = 0; e < MM; ++e) c += (idx[(i * MM + e) << i64] >= 0) ? 1 : 0;
    dis[i] = rsqrtf((float)c);
  } else if (bid < 40) {
    const int id = (bid - 32) * 256 + tid;  // 0..2047
    const int q = id >> 9;
    const void* src = q == 0 ? b0 : q == 1 ? b1 : q == 2 ? b2 : b3;
    const int off = id & (HH - 1);
    bf16 v = f32in ? (bf16)((const float*)src)[off] : ((const bf16*)src)[off];
    biasBF[id] = *(u16*)&v;
  } else {
    int t = bid - 40;  // 0..831: Wemb 64 tiles, W1/2/3 256 each (32x32 tiles)
    const void* W;
    u16* T;
    int K, tt;
    if (t < 64) {
      W = Wemb; T = TWemb; K = FN; tt = t;
    } else {
      int q = (t - 64) >> 8;
      tt = (t - 64) & 255;
      K = HH;
      W = q == 0 ? W1 : q == 1 ? W2 : W3;
      T = q == 0 ? TW1 : q == 1 ? TW2 : TW3;
    }
    const int k0 = (tt >> 4) * 32, n0 = (tt & 15) * 32;
    __shared__ u16 sm[32 * 33];
    const int tx = tid & 31, ty = tid >> 5;  // ty 0..7
#pragma unroll
    for (int r = ty; r < 32; r += 8) {
      size_t src = (size_t)(k0 + r) * HH + n0 + tx;
      bf16 v = f32in ? (bf16)((const float*)W)[src] : ((const bf16*)W)[src];
      sm[r * 33 + tx] = *(u16*)&v;
    }
    __syncthreads();
#pragma unroll
    for (int r = ty; r < 32; r += 8)
      T[(size_t)(n0 + r) * K + k0 + tx] = sm[tx * 33 + r];
  }
}

// ---- GEMM: C[rtile*64..+64][ctile*128..+128] = A @ Bt^T + bias
// 256 thr / 4 waves (2x2), wave 32x64 (2x4 accs of 16x16x32), BK=64,
// gld_lds + XOR swizzle: LDS chunk (row, cc) holds k-chunk gc = cc ^ (row&7).
// R5-verified correct, 0 bank conflicts. grid (128,4) = 512 blocks = 2/CU.
template <bool RELU>
__device__ __forceinline__ void gemm_tile(const void* __restrict__ A, int K,
                                          int af32, const u16* __restrict__ Bt,
                                          const u16* __restrict__ bias,
                                          int rtile, int ctile, int outf32,
                                          void* __restrict__ C, u16* As,
                                          u16* Bs) {
  const int tid = threadIdx.x;
  const int wave = tid >> 6, lane = tid & 63;
  const int wr = wave >> 1, wc = wave & 1;
  const int quad = lane >> 4, l16 = lane & 15;
  f32x4 acc[2][4] = {};

  int arow[2], agc[2], brow[4], bgc[4];
#pragma unroll
  for (int i = 0; i < 2; ++i) {
    int c = i * 256 + tid;
    arow[i] = c >> 3;
    agc[i] = (c & 7) ^ (arow[i] & 7);
  }
#pragma unroll
  for (int i = 0; i < 4; ++i) {
    int c = i * 256 + tid;
    brow[i] = c >> 3;
    bgc[i] = (c & 7) ^ (brow[i] & 7);
  }
  u16* AsW = As + wave * 512;  // wave-uniform LDS bases (chunk c -> c*16 B)
  u16* BsW = Bs + wave * 512;

  for (int k0 = 0; k0 < K; k0 += 64) {
    __syncthreads();  // prev iter's ds_reads done
    if (af32) {
      const float* Af = (const float*)A;
      bf16x8 v[2];
#pragma unroll
      for (int i = 0; i < 2; ++i) {
        const float* p = &Af[(size_t)(rtile * 64 + arow[i]) * K + k0 + agc[i] * 8];
        f32x4 x0 = *(const f32x4*)p, x1 = *(const f32x4*)(p + 4);
#pragma unroll
        for (int t = 0; t < 4; ++t) {
          v[i][t] = (bf16)x0[t];
          v[i][4 + t] = (bf16)x1[t];
        }
      }
#pragma unroll
      for (int i = 0; i < 2; ++i) *(bf16x8*)&As[(i * 256 + tid) * 8] = v[i];
    } else {
      const u16* Ab = (const u16*)A;
#pragma unroll
      for (int i = 0; i < 2; ++i)
        gld_lds16(&Ab[(size_t)(rtile * 64 + arow[i]) * K + k0 + agc[i] * 8],
                  AsW + i * 2048);
    }
#pragma unroll
    for (int i = 0; i < 4; ++i)
      gld_lds16(&Bt[(size_t)(ctile * 128 + brow[i]) * K + k0 + bgc[i] * 8],
                BsW + i * 2048);
    __syncthreads();  // drains vmcnt (DMA complete)
#pragma unroll
    for (int h = 0; h < 2; ++h) {
      bf16x8 af[2], bfr[4];
#pragma unroll
      for (int i = 0; i < 2; ++i) {
        int r = wr * 32 + i * 16 + l16;
        int cc = (h * 4 + quad) ^ (r & 7);
        af[i] = *(const bf16x8*)&As[r * 64 + cc * 8];
      }
#pragma unroll
      for (int j = 0; j < 4; ++j) {
        int n = wc * 64 + j * 16 + l16;
        int cc = (h * 4 + quad) ^ (n & 7);
        bfr[j] = *(const bf16x8*)&Bs[n * 64 + cc * 8];
      }
#pragma unroll
      for (int i = 0; i < 2; ++i)
#pragma unroll
        for (int j = 0; j < 4; ++j)
          acc[i][j] = __builtin_amdgcn_mfma_f32_16x16x32_bf16(af[i], bfr[j],
                                                              acc[i][j], 0, 0, 0);
    }
  }

  // C/D layout: col = lane&15, row = quad*4 + reg (m89/m91)
  const int crow0 = rtile * 64 + wr * 32 + quad * 4;
  const int ccol0 = ctile * 128 + wc * 64 + l16;
#pragma unroll
  for (int j = 0; j < 4; ++j) {
    const int col = ccol0 + j * 16;
    const float bv = (float)(*(const bf16*)&bias[col]);
#pragma unroll
    for (int i = 0; i < 2; ++i)
#pragma unroll
      for (int r = 0; r < 4; ++r) {
        float v = acc[i][j][r] + bv;
        if (RELU) v = fmaxf(v, 0.0f);
        size_t off = (size_t)(crow0 + i * 16 + r) * HH + col;
        if (outf32) {
          ((float*)C)[off] = v;
        } else {
          bf16 o = (bf16)v;
          ((u16*)C)[off] = *(u16*)&o;
        }
      }
  }
}

__global__ __launch_bounds__(256) void gemm_emb(const void* __restrict__ A,
                                                const u16* __restrict__ Bt,
                                                const u16* __restrict__ bias,
                                                u16* __restrict__ C) {
  __shared__ __align__(16) u16 As[64 * 64];
  __shared__ __align__(16) u16 Bs[128 * 64];
  const int af32 = probe_f32((const u16*)A);  // A is the raw node input
  gemm_tile<false>(A, FN, af32, Bt, bias, blockIdx.x, blockIdx.y, 0, C, As, Bs);
}

template <bool RELU, bool FINAL>
__global__ __launch_bounds__(256) void gemm_main(const u16* __restrict__ A,
                                                 const u16* __restrict__ Bt,
                                                 const u16* __restrict__ bias,
                                                 const u16* __restrict__ nodeprobe,
                                                 void* __restrict__ C) {
  __shared__ __align__(16) u16 As[64 * 64];
  __shared__ __align__(16) u16 Bs[128 * 64];
  int outf32 = 0;
  if (FINAL) outf32 = probe_f32(nodeprobe);
  gemm_tile<RELU>(A, HH, 0, Bt, bias, blockIdx.x, blockIdx.y, outf32, C, As, Bs);
}

// ---- agg: y[i,:] = d[i]*( d[i]*x[i,:] + sum_e d[j]*x[j,:] ); wave per node,
// 2048 blocks x 4 waves = full occupancy for gather-latency hiding.
__global__ __launch_bounds__(256) void agg_kernel(const u16* __restrict__ x,
                                                  const u32* __restrict__ idxw,
                                                  const float* __restrict__ dis,
                                                  u16* __restrict__ y) {
  const int i64 = probe_i64(idxw);
  const int* idx = (const int*)idxw;
  const int node = blockIdx.x * 4 + (threadIdx.x >> 6);
  const int lane = threadIdx.x & 63;
  const int c0 = lane * 8;
  const float wi = dis[node];
  float acc[8];
  bf16x8 xs = *(const bf16x8*)&x[(size_t)node * HH + c0];
#pragma unroll
  for (int t = 0; t < 8; ++t) acc[t] = wi * wi * (float)xs[t];
#pragma unroll
  for (int e = 0; e < MM; ++e) {
    const int j = idx[(node * MM + e) << i64];
    if (j >= 0) {
      const float w = wi * dis[j];
      bf16x8 v = *(const bf16x8*)&x[(size_t)j * HH + c0];
#pragma unroll
      for (int t = 0; t < 8; ++t) acc[t] += w * (float)v[t];
    }
  }
  bf16x8 o;
#pragma unroll
  for (int t = 0; t < 8; ++t) o[t] = (bf16)acc[t];
  *(bf16x8*)&y[(size_t)node * HH + c0] = o;
}

extern "C" void kernel_launch(void* const* d_in, const int* in_sizes, int n_in,
                              void* d_out, int out_size, void* d_ws, size_t ws_size,
                              hipStream_t stream) {
  const u16* node = (const u16*)d_in[0];
  const u32* idxw = (const u32*)d_in[1];
  const void* Wemb = d_in[2];
  const void* bemb = d_in[3];
  const void* W1 = d_in[4];
  const void* b1 = d_in[5];
  const void* W2 = d_in[6];
  const void* b2 = d_in[7];
  const void* W3 = d_in[8];
  const void* b3 = d_in[9];

  char* p = (char*)d_ws;
  float* dis = (float*)p;  p += NN * sizeof(float);
  u16* biasBF = (u16*)p;   p += 4 * HH * sizeof(u16);
  u16* TWemb = (u16*)p;    p += (size_t)HH * FN * 2;
  u16* TW1 = (u16*)p;      p += (size_t)HH * HH * 2;
  u16* TW2 = (u16*)p;      p += (size_t)HH * HH * 2;
  u16* TW3 = (u16*)p;      p += (size_t)HH * HH * 2;
  u16* xA = (u16*)p;
  u16* xO = (u16*)d_out;  // d_out doubles as bf16 ping buffer

  prep_kernel<<<872, 256, 0, stream>>>(node, idxw, Wemb, bemb, W1, b1, W2, b2,
                                       W3, b3, dis, biasBF, TWemb, TW1, TW2, TW3);
  gemm_emb<<<dim3(128, 4), 256, 0, stream>>>(node, TWemb, biasBF, xO);
  agg_kernel<<<NN / 4, 256, 0, stream>>>(xO, idxw, dis, xA);
  gemm_main<true, false>
      <<<dim3(128, 4), 256, 0, stream>>>(xA, TW1, biasBF + HH, node, xO);
  agg_kernel<<<NN / 4, 256, 0, stream>>>(xO, idxw, dis, xA);
  gemm_main<true, false>
      <<<dim3(128, 4), 256, 0, stream>>>(xA, TW2, biasBF + 2 * HH, node, xO);
  agg_kernel<<<NN / 4, 256, 0, stream>>>(xO, idxw, dis, xA);
  gemm_main<false, true>
      <<<dim3(128, 4), 256, 0, stream>>>(xA, TW3, biasBF + 3 * HH, node, d_out);
}

// Round 7
// 170.361 us; speedup vs baseline: 6.8218x; 1.0564x over previous
//
#include <hip/hip_runtime.h>
#include <stdint.h>

#define NN 8192
#define MM 16
#define FN 128
#define HH 512

typedef unsigned short u16;
typedef unsigned int u32;
typedef __bf16 bf16;
typedef __bf16 bf16x8 __attribute__((ext_vector_type(8)));
typedef float f32x4 __attribute__((ext_vector_type(4)));

// async global->LDS, 16B/lane; LDS dest = wave-uniform base + lane*16
__device__ __forceinline__ void gld_lds16(const u16* g, u16* l) {
  __builtin_amdgcn_global_load_lds(
      (const __attribute__((address_space(1))) void*)g,
      (__attribute__((address_space(3))) void*)l, 16, 0, 0);
}

// ---- dtype probes (per-wave; ~2 cached loads + ballot) ----
__device__ __forceinline__ int probe_f32(const u16* w) {
  int lane = threadIdx.x & 63;
  int e = (w[2 * lane] >> 7) & 0xFF;
  unsigned long long m = __ballot(!(e == 0 || (e >= 90 && e <= 140)));
  return __popcll(m) >= 8;
}
__device__ __forceinline__ int probe_i64(const u32* w) {
  int lane = threadIdx.x & 63;
  unsigned long long m = __ballot(lane < 32 && w[2 * lane + 1] != 0);
  return m == 0;
}

// ---- transpose one 32x32 tile of W (K x 512) -> T (512 x K) ----
__device__ __forceinline__ void transpose_tile(const void* __restrict__ W,
                                               u16* __restrict__ T, int K,
                                               int tt, int f32in, u16* sm) {
  const int k0 = (tt >> 4) * 32, n0 = (tt & 15) * 32;
  const int tx = threadIdx.x & 31, ty = threadIdx.x >> 5;  // ty 0..7
#pragma unroll
  for (int r = ty; r < 32; r += 8) {
    size_t src = (size_t)(k0 + r) * HH + n0 + tx;
    bf16 v = f32in ? (bf16)((const float*)W)[src] : ((const bf16*)W)[src];
    sm[r * 33 + tx] = *(u16*)&v;
  }
  __syncthreads();
#pragma unroll
  for (int r = ty; r < 32; r += 8)
    T[(size_t)(n0 + r) * K + k0 + tx] = sm[tx * 33 + r];
}

// ---- prepA: bias_emb (blocks 0..1) + TWemb transpose (blocks 2..65) ----
__global__ __launch_bounds__(256) void prepA_kernel(
    const u16* __restrict__ node, const void* __restrict__ Wemb,
    const void* __restrict__ b0, u16* __restrict__ biasBF,
    u16* __restrict__ TWemb) {
  __shared__ u16 sm[32 * 33];
  const int f32in = probe_f32(node);
  const int bid = blockIdx.x, tid = threadIdx.x;
  if (bid < 2) {
    const int off = bid * 256 + tid;  // 0..511
    bf16 v = f32in ? (bf16)((const float*)b0)[off] : ((const bf16*)b0)[off];
    biasBF[off] = *(u16*)&v;
  } else {
    transpose_tile(Wemb, TWemb, FN, bid - 2, f32in, sm);
  }
}

// ---- GEMM tile: C[rtile*64..+64][ctile*128..+128] = A @ Bt^T + bias
// 256 thr / 4 waves (2x2), wave 32x64 (2x4 accs of 16x16x32), BK=64,
// gld_lds + XOR swizzle (LDS chunk (row,cc) holds k-chunk gc = cc^(row&7)).
// R5/R6-verified: correct, 0 bank conflicts.
template <bool RELU>
__device__ __forceinline__ void gemm_tile(const void* __restrict__ A, int K,
                                          int af32, const u16* __restrict__ Bt,
                                          const u16* __restrict__ bias,
                                          int rtile, int ctile, int outf32,
                                          void* __restrict__ C, u16* As,
                                          u16* Bs) {
  const int tid = threadIdx.x;
  const int wave = tid >> 6, lane = tid & 63;
  const int wr = wave >> 1, wc = wave & 1;
  const int quad = lane >> 4, l16 = lane & 15;
  f32x4 acc[2][4] = {};

  int arow[2], agc[2], brow[4], bgc[4];
#pragma unroll
  for (int i = 0; i < 2; ++i) {
    int c = i * 256 + tid;
    arow[i] = c >> 3;
    agc[i] = (c & 7) ^ (arow[i] & 7);
  }
#pragma unroll
  for (int i = 0; i < 4; ++i) {
    int c = i * 256 + tid;
    brow[i] = c >> 3;
    bgc[i] = (c & 7) ^ (brow[i] & 7);
  }
  u16* AsW = As + wave * 512;  // wave-uniform LDS bases (chunk c -> c*16 B)
  u16* BsW = Bs + wave * 512;

  for (int k0 = 0; k0 < K; k0 += 64) {
    __syncthreads();  // prev iter's ds_reads done
    if (af32) {
      const float* Af = (const float*)A;
      bf16x8 v[2];
#pragma unroll
      for (int i = 0; i < 2; ++i) {
        const float* p = &Af[(size_t)(rtile * 64 + arow[i]) * K + k0 + agc[i] * 8];
        f32x4 x0 = *(const f32x4*)p, x1 = *(const f32x4*)(p + 4);
#pragma unroll
        for (int t = 0; t < 4; ++t) {
          v[i][t] = (bf16)x0[t];
          v[i][4 + t] = (bf16)x1[t];
        }
      }
#pragma unroll
      for (int i = 0; i < 2; ++i) *(bf16x8*)&As[(i * 256 + tid) * 8] = v[i];
    } else {
      const u16* Ab = (const u16*)A;
#pragma unroll
      for (int i = 0; i < 2; ++i)
        gld_lds16(&Ab[(size_t)(rtile * 64 + arow[i]) * K + k0 + agc[i] * 8],
                  AsW + i * 2048);
    }
#pragma unroll
    for (int i = 0; i < 4; ++i)
      gld_lds16(&Bt[(size_t)(ctile * 128 + brow[i]) * K + k0 + bgc[i] * 8],
                BsW + i * 2048);
    __syncthreads();  // drains vmcnt (DMA complete)
#pragma unroll
    for (int h = 0; h < 2; ++h) {
      bf16x8 af[2], bfr[4];
#pragma unroll
      for (int i = 0; i < 2; ++i) {
        int r = wr * 32 + i * 16 + l16;
        int cc = (h * 4 + quad) ^ (r & 7);
        af[i] = *(const bf16x8*)&As[r * 64 + cc * 8];
      }
#pragma unroll
      for (int j = 0; j < 4; ++j) {
        int n = wc * 64 + j * 16 + l16;
        int cc = (h * 4 + quad) ^ (n & 7);
        bfr[j] = *(const bf16x8*)&Bs[n * 64 + cc * 8];
      }
#pragma unroll
      for (int i = 0; i < 2; ++i)
#pragma unroll
        for (int j = 0; j < 4; ++j)
          acc[i][j] = __builtin_amdgcn_mfma_f32_16x16x32_bf16(af[i], bfr[j],
                                                              acc[i][j], 0, 0, 0);
    }
  }

  // C/D layout: col = lane&15, row = quad*4 + reg (m89/m91)
  const int crow0 = rtile * 64 + wr * 32 + quad * 4;
  const int ccol0 = ctile * 128 + wc * 64 + l16;
#pragma unroll
  for (int j = 0; j < 4; ++j) {
    const int col = ccol0 + j * 16;
    const float bv = (float)(*(const bf16*)&bias[col]);
#pragma unroll
    for (int i = 0; i < 2; ++i)
#pragma unroll
      for (int r = 0; r < 4; ++r) {
        float v = acc[i][j][r] + bv;
        if (RELU) v = fmaxf(v, 0.0f);
        size_t off = (size_t)(crow0 + i * 16 + r) * HH + col;
        if (outf32) {
          ((float*)C)[off] = v;
        } else {
          bf16 o = (bf16)v;
          ((u16*)C)[off] = *(u16*)&o;
        }
      }
  }
}

// ---- launch B: emb GEMM (blocks 0..511) + deg (512..543) +
//      bias1/2/3 (544..549) + TW1/2/3 transpose (550..1317).
// Extra blocks are independent of the GEMM part; they fill idle CUs.
__global__ __launch_bounds__(256) void emb_plus_kernel(
    const u16* __restrict__ node, const u32* __restrict__ idxw,
    const void* __restrict__ W1, const void* __restrict__ b1,
    const void* __restrict__ W2, const void* __restrict__ b2,
    const void* __restrict__ W3, const void* __restrict__ b3,
    const u16* __restrict__ TWemb, const u16* __restrict__ biasBF,
    float* __restrict__ dis, u16* __restrict__ biasBF_w,
    u16* __restrict__ TW1, u16* __restrict__ TW2, u16* __restrict__ TW3,
    u16* __restrict__ xout) {
  __shared__ __align__(16) u16 As[64 * 64];
  __shared__ __align__(16) u16 Bs[128 * 64];
  const int bid = blockIdx.x, tid = threadIdx.x;
  if (bid < 512) {
    const int af32 = probe_f32(node);
    gemm_tile<false>(node, FN, af32, TWemb, biasBF, bid >> 2, bid & 3, 0, xout,
                     As, Bs);
  } else if (bid < 544) {
    const int i64 = probe_i64(idxw);
    const int* idx = (const int*)idxw;
    const int i = (bid - 512) * 256 + tid;
    int c = 1;
#pragma unroll
    for (int e = 0; e < MM; ++e) c += (idx[(i * MM + e) << i64] >= 0) ? 1 : 0;
    dis[i] = rsqrtf((float)c);
  } else if (bid < 550) {
    const int f32in = probe_f32(node);
    const int id = (bid - 544) * 256 + tid;  // 0..1535 over b1,b2,b3
    const int q = id >> 9;
    const void* src = q == 0 ? b1 : q == 1 ? b2 : b3;
    const int off = id & (HH - 1);
    bf16 v = f32in ? (bf16)((const float*)src)[off] : ((const bf16*)src)[off];
    biasBF_w[HH + id] = *(u16*)&v;
  } else {
    const int f32in = probe_f32(node);
    const int t = bid - 550;  // 0..767
    const int q = t >> 8, tt = t & 255;
    const void* W = q == 0 ? W1 : q == 1 ? W2 : W3;
    u16* T = q == 0 ? TW1 : q == 1 ? TW2 : TW3;
    transpose_tile(W, T, HH, tt, f32in, As);
  }
}

template <bool RELU, bool FINAL>
__global__ __launch_bounds__(256) void gemm_main(const u16* __restrict__ A,
                                                 const u16* __restrict__ Bt,
                                                 const u16* __restrict__ bias,
                                                 const u16* __restrict__ nodeprobe,
                                                 void* __restrict__ C) {
  __shared__ __align__(16) u16 As[64 * 64];
  __shared__ __align__(16) u16 Bs[128 * 64];
  int outf32 = 0;
  if (FINAL) outf32 = probe_f32(nodeprobe);
  gemm_tile<RELU>(A, HH, 0, Bt, bias, blockIdx.x, blockIdx.y, outf32, C, As, Bs);
}

// ---- agg: y[i,:] = d[i]*( d[i]*x[i,:] + sum_e d[j]*x[j,:] )
// XCD-pinned column strips: strip s (128 cols, 2 MB of x) is only read by
// blocks with blockIdx%8 in {2s,2s+1} -> resident in that XCD-pair's L2.
// 16 lanes per node-strip; wave covers 4 nodes; block 16 nodes.
__global__ __launch_bounds__(256) void agg_kernel(const u16* __restrict__ x,
                                                  const u32* __restrict__ idxw,
                                                  const float* __restrict__ dis,
                                                  u16* __restrict__ y) {
  const int i64 = probe_i64(idxw);
  const int* idx = (const int*)idxw;
  const int b = blockIdx.x;
  const int strip = (b & 7) >> 1;           // 0..3, pinned to XCD pair
  const int grp = (b >> 3) * 2 + (b & 1);   // 0..511 node group
  const int wave = threadIdx.x >> 6, lane = threadIdx.x & 63;
  const int node = grp * 16 + wave * 4 + (lane >> 4);
  const int c0 = strip * 128 + (lane & 15) * 8;
  const float wi = dis[node];
  float acc[8];
  bf16x8 xs = *(const bf16x8*)&x[(size_t)node * HH + c0];
#pragma unroll
  for (int t = 0; t < 8; ++t) acc[t] = wi * wi * (float)xs[t];
#pragma unroll
  for (int e = 0; e < MM; ++e) {
    const int j = idx[(node * MM + e) << i64];
    if (j >= 0) {
      const float w = wi * dis[j];
      bf16x8 v = *(const bf16x8*)&x[(size_t)j * HH + c0];
#pragma unroll
      for (int t = 0; t < 8; ++t) acc[t] += w * (float)v[t];
    }
  }
  bf16x8 o;
#pragma unroll
  for (int t = 0; t < 8; ++t) o[t] = (bf16)acc[t];
  *(bf16x8*)&y[(size_t)node * HH + c0] = o;
}

extern "C" void kernel_launch(void* const* d_in, const int* in_sizes, int n_in,
                              void* d_out, int out_size, void* d_ws, size_t ws_size,
                              hipStream_t stream) {
  const u16* node = (const u16*)d_in[0];
  const u32* idxw = (const u32*)d_in[1];
  const void* Wemb = d_in[2];
  const void* bemb = d_in[3];
  const void* W1 = d_in[4];
  const void* b1 = d_in[5];
  const void* W2 = d_in[6];
  const void* b2 = d_in[7];
  const void* W3 = d_in[8];
  const void* b3 = d_in[9];

  char* p = (char*)d_ws;
  float* dis = (float*)p;  p += NN * sizeof(float);
  u16* biasBF = (u16*)p;   p += 4 * HH * sizeof(u16);
  u16* TWemb = (u16*)p;    p += (size_t)HH * FN * 2;
  u16* TW1 = (u16*)p;      p += (size_t)HH * HH * 2;
  u16* TW2 = (u16*)p;      p += (size_t)HH * HH * 2;
  u16* TW3 = (u16*)p;      p += (size_t)HH * HH * 2;
  u16* xA = (u16*)p;
  u16* xO = (u16*)d_out;  // d_out doubles as bf16 ping buffer

  prepA_kernel<<<66, 256, 0, stream>>>(node, Wemb, bemb, biasBF, TWemb);
  emb_plus_kernel<<<1318, 256, 0, stream>>>(node, idxw, W1, b1, W2, b2, W3, b3,
                                            TWemb, biasBF, dis, biasBF, TW1,
                                            TW2, TW3, xO);
  agg_kernel<<<NN / 4, 256, 0, stream>>>(xO, idxw, dis, xA);
  gemm_main<true, false>
      <<<dim3(128, 4), 256, 0, stream>>>(xA, TW1, biasBF + HH, node, xO);
  agg_kernel<<<NN / 4, 256, 0, stream>>>(xO, idxw, dis, xA);
  gemm_main<true, false>
      <<<dim3(128, 4), 256, 0, stream>>>(xA, TW2, biasBF + 2 * HH, node, xO);
  agg_kernel<<<NN / 4, 256, 0, stream>>>(xO, idxw, dis, xA);
  gemm_main<false, true>
      <<<dim3(128, 4), 256, 0, stream>>>(xA, TW3, biasBF + 3 * HH, node, d_out);
}